// Round 2
// baseline (407.368 us; speedup 1.0000x reference)
//
#include <hip/hip_runtime.h>
#include <math.h>

#define DD 32
#define GREC 136   // floats per group record: s[16] | P[3][8] | me[3][32]
#define IREC 56    // floats per item record:  t[16] | Q[8] | ie[32]

// ---------------- precompute: one thread per group ----------------
__global__ __launch_bounds__(256) void grp_pre(
    const int* __restrict__ gm, const float* __restrict__ ue,
    const float* __restrict__ w1, const float* __restrict__ b1,
    const float* __restrict__ pw1,
    float* __restrict__ grec, int NG)
{
    int g = blockIdx.x * blockDim.x + threadIdx.x;
    if (g >= NG) return;
    float* rec = grec + (size_t)g * GREC;

    float s[16];
    #pragma unroll
    for (int j = 0; j < 16; ++j) s[j] = b1[j];

    #pragma unroll
    for (int m = 0; m < 3; ++m) {
        int u = gm[3 * g + m];
        const float4* p = reinterpret_cast<const float4*>(ue + (size_t)u * DD);
        float mv[DD];
        #pragma unroll
        for (int q = 0; q < 8; ++q) {
            float4 v = p[q];
            mv[4*q] = v.x; mv[4*q+1] = v.y; mv[4*q+2] = v.z; mv[4*q+3] = v.w;
        }
        float Pm[8];
        #pragma unroll
        for (int j = 0; j < 8; ++j) Pm[j] = 0.0f;
        #pragma unroll
        for (int d = 0; d < DD; ++d) {
            float x = mv[d];
            #pragma unroll
            for (int j = 0; j < 16; ++j)
                s[j] = fmaf(x, w1[(m * DD + d) * 16 + j], s[j]);
            #pragma unroll
            for (int j = 0; j < 8; ++j)
                Pm[j] = fmaf(x, pw1[(DD + d) * 8 + j], Pm[j]);   // B block
        }
        // store P[m] and me[m] (16B-aligned offsets: 16+8m and 40+32m floats)
        reinterpret_cast<float4*>(rec + 16 + m * 8)[0] = make_float4(Pm[0], Pm[1], Pm[2], Pm[3]);
        reinterpret_cast<float4*>(rec + 16 + m * 8)[1] = make_float4(Pm[4], Pm[5], Pm[6], Pm[7]);
        #pragma unroll
        for (int q = 0; q < 8; ++q)
            reinterpret_cast<float4*>(rec + 40 + m * DD)[q] =
                make_float4(mv[4*q], mv[4*q+1], mv[4*q+2], mv[4*q+3]);
    }
    #pragma unroll
    for (int q = 0; q < 4; ++q)
        reinterpret_cast<float4*>(rec)[q] = make_float4(s[4*q], s[4*q+1], s[4*q+2], s[4*q+3]);
}

// ---------------- precompute: one thread per item ----------------
__global__ __launch_bounds__(256) void item_pre(
    const float* __restrict__ itemb,
    const float* __restrict__ w1,
    const float* __restrict__ pw1, const float* __restrict__ pb1,
    float* __restrict__ irec, int NI)
{
    int i = blockIdx.x * blockDim.x + threadIdx.x;
    if (i >= NI) return;
    float* rec = irec + (size_t)i * IREC;

    const float4* p = reinterpret_cast<const float4*>(itemb + (size_t)i * DD);
    float ev[DD];
    #pragma unroll
    for (int q = 0; q < 8; ++q) {
        float4 v = p[q];
        ev[4*q] = v.x; ev[4*q+1] = v.y; ev[4*q+2] = v.z; ev[4*q+3] = v.w;
    }
    float t[16];
    #pragma unroll
    for (int j = 0; j < 16; ++j) t[j] = 0.0f;
    float Q[8];
    #pragma unroll
    for (int j = 0; j < 8; ++j) Q[j] = pb1[j];
    #pragma unroll
    for (int d = 0; d < DD; ++d) {
        float x = ev[d];
        #pragma unroll
        for (int j = 0; j < 16; ++j)
            t[j] = fmaf(x, w1[(3 * DD + d) * 16 + j], t[j]);
        #pragma unroll
        for (int j = 0; j < 8; ++j)
            Q[j] = fmaf(x, pw1[(2 * DD + d) * 8 + j], Q[j]);     // C block
    }
    #pragma unroll
    for (int q = 0; q < 4; ++q)
        reinterpret_cast<float4*>(rec)[q] = make_float4(t[4*q], t[4*q+1], t[4*q+2], t[4*q+3]);
    reinterpret_cast<float4*>(rec + 16)[0] = make_float4(Q[0], Q[1], Q[2], Q[3]);
    reinterpret_cast<float4*>(rec + 16)[1] = make_float4(Q[4], Q[5], Q[6], Q[7]);
    #pragma unroll
    for (int q = 0; q < 8; ++q)
        reinterpret_cast<float4*>(rec + 24)[q] = make_float4(ev[4*q], ev[4*q+1], ev[4*q+2], ev[4*q+3]);
}

// ---------------- main: one thread per batch element ----------------
__global__ __launch_bounds__(256) void agree_main(
    const int* __restrict__ gi, const int* __restrict__ ii,
    const float* __restrict__ grec, const float* __restrict__ irec,
    const float* __restrict__ w2, const float* __restrict__ b2,
    const float* __restrict__ pw1, const float* __restrict__ pw2,
    const float* __restrict__ pb2,
    float* __restrict__ out, int B)
{
    int b = blockIdx.x * blockDim.x + threadIdx.x;
    if (b >= B) return;

    const float* gr = grec + (size_t)gi[b] * GREC;
    const float* ir = irec + (size_t)ii[b] * IREC;
    const float4* gr4 = reinterpret_cast<const float4*>(gr);
    const float4* ir4 = reinterpret_cast<const float4*>(ir);

    // h = relu(s_g + t_i)   (b1 baked into s_g)
    float h[16];
    #pragma unroll
    for (int q = 0; q < 4; ++q) {
        float4 a = gr4[q];
        float4 c = ir4[q];
        h[4*q+0] = fmaxf(a.x + c.x, 0.0f);
        h[4*q+1] = fmaxf(a.y + c.y, 0.0f);
        h[4*q+2] = fmaxf(a.z + c.z, 0.0f);
        h[4*q+3] = fmaxf(a.w + c.w, 0.0f);
    }

    // logits + softmax over 3 members
    float l0 = b2[0], l1 = b2[1], l2 = b2[2];
    #pragma unroll
    for (int j = 0; j < 16; ++j) {
        l0 = fmaf(h[j], w2[j * 3 + 0], l0);
        l1 = fmaf(h[j], w2[j * 3 + 1], l1);
        l2 = fmaf(h[j], w2[j * 3 + 2], l2);
    }
    float mx = fmaxf(l0, fmaxf(l1, l2));
    float e0 = __expf(l0 - mx);
    float e1 = __expf(l1 - mx);
    float e2 = __expf(l2 - mx);
    float inv = 1.0f / (e0 + e1 + e2);
    float wt0 = e0 * inv, wt1 = e1 * inv, wt2 = e2 * inv;

    // h2 = Q_i (pb1 baked) + sum_m wt_m P_g[m] + sum_d (g*ie)_d A[d]
    float h2[8];
    {
        float4 q0 = ir4[4], q1 = ir4[5];
        h2[0] = q0.x; h2[1] = q0.y; h2[2] = q0.z; h2[3] = q0.w;
        h2[4] = q1.x; h2[5] = q1.y; h2[6] = q1.z; h2[7] = q1.w;
    }
    #pragma unroll
    for (int m = 0; m < 3; ++m) {
        float wm = (m == 0) ? wt0 : (m == 1) ? wt1 : wt2;
        float4 p0 = gr4[4 + 2 * m];
        float4 p1 = gr4[5 + 2 * m];
        h2[0] = fmaf(wm, p0.x, h2[0]); h2[1] = fmaf(wm, p0.y, h2[1]);
        h2[2] = fmaf(wm, p0.z, h2[2]); h2[3] = fmaf(wm, p0.w, h2[3]);
        h2[4] = fmaf(wm, p1.x, h2[4]); h2[5] = fmaf(wm, p1.y, h2[5]);
        h2[6] = fmaf(wm, p1.z, h2[6]); h2[7] = fmaf(wm, p1.w, h2[7]);
    }

    const float4* me4 = reinterpret_cast<const float4*>(gr + 40);
    const float4* ie4 = reinterpret_cast<const float4*>(ir + 24);
    #pragma unroll
    for (int q = 0; q < 8; ++q) {
        float4 a0 = me4[q];
        float4 a1 = me4[8 + q];
        float4 a2 = me4[16 + q];
        float4 e  = ie4[q];
        float g0 = fmaf(wt0, a0.x, fmaf(wt1, a1.x, wt2 * a2.x)) * e.x;
        float g1 = fmaf(wt0, a0.y, fmaf(wt1, a1.y, wt2 * a2.y)) * e.y;
        float g2 = fmaf(wt0, a0.z, fmaf(wt1, a1.z, wt2 * a2.z)) * e.z;
        float g3 = fmaf(wt0, a0.w, fmaf(wt1, a1.w, wt2 * a2.w)) * e.w;
        #pragma unroll
        for (int j = 0; j < 8; ++j) {
            h2[j] = fmaf(g0, pw1[(4*q+0) * 8 + j], h2[j]);
            h2[j] = fmaf(g1, pw1[(4*q+1) * 8 + j], h2[j]);
            h2[j] = fmaf(g2, pw1[(4*q+2) * 8 + j], h2[j]);
            h2[j] = fmaf(g3, pw1[(4*q+3) * 8 + j], h2[j]);
        }
    }

    float z = pb2[0];
    #pragma unroll
    for (int j = 0; j < 8; ++j)
        z = fmaf(fmaxf(h2[j], 0.0f), pw2[j], z);

    out[b] = 1.0f / (1.0f + __expf(-z));
}

// ---------------- fallback (round-1 kernel) if ws too small ----------------
__global__ __launch_bounds__(256) void agree_fwd(
    const int* __restrict__ gi, const int* __restrict__ ii,
    const int* __restrict__ gm,
    const float* __restrict__ ue, const float* __restrict__ itemb,
    const float* __restrict__ w1, const float* __restrict__ b1,
    const float* __restrict__ w2, const float* __restrict__ b2,
    const float* __restrict__ pw1, const float* __restrict__ pb1,
    const float* __restrict__ pw2, const float* __restrict__ pb2,
    float* __restrict__ out, int B)
{
    int b = blockIdx.x * blockDim.x + threadIdx.x;
    if (b >= B) return;
    int g = gi[b], it = ii[b];
    int m0 = gm[3*g+0], m1 = gm[3*g+1], m2 = gm[3*g+2];
    float me[3][DD], iev[DD];
    {
        const float4* p0 = reinterpret_cast<const float4*>(ue + (size_t)m0 * DD);
        const float4* p1 = reinterpret_cast<const float4*>(ue + (size_t)m1 * DD);
        const float4* p2 = reinterpret_cast<const float4*>(ue + (size_t)m2 * DD);
        const float4* p3 = reinterpret_cast<const float4*>(itemb + (size_t)it * DD);
        #pragma unroll
        for (int q = 0; q < 8; ++q) {
            float4 v0 = p0[q], v1 = p1[q], v2 = p2[q], v3 = p3[q];
            me[0][4*q]=v0.x; me[0][4*q+1]=v0.y; me[0][4*q+2]=v0.z; me[0][4*q+3]=v0.w;
            me[1][4*q]=v1.x; me[1][4*q+1]=v1.y; me[1][4*q+2]=v1.z; me[1][4*q+3]=v1.w;
            me[2][4*q]=v2.x; me[2][4*q+1]=v2.y; me[2][4*q+2]=v2.z; me[2][4*q+3]=v2.w;
            iev[4*q]=v3.x; iev[4*q+1]=v3.y; iev[4*q+2]=v3.z; iev[4*q+3]=v3.w;
        }
    }
    float h[16];
    #pragma unroll
    for (int j = 0; j < 16; ++j) h[j] = b1[j];
    #pragma unroll
    for (int m = 0; m < 3; ++m)
        #pragma unroll
        for (int k = 0; k < DD; ++k) {
            float xk = me[m][k];
            #pragma unroll
            for (int j = 0; j < 16; ++j)
                h[j] = fmaf(xk, w1[(m*DD+k)*16+j], h[j]);
        }
    #pragma unroll
    for (int k = 0; k < DD; ++k) {
        float xk = iev[k];
        #pragma unroll
        for (int j = 0; j < 16; ++j)
            h[j] = fmaf(xk, w1[(3*DD+k)*16+j], h[j]);
    }
    #pragma unroll
    for (int j = 0; j < 16; ++j) h[j] = fmaxf(h[j], 0.0f);
    float l0 = b2[0], l1 = b2[1], l2 = b2[2];
    #pragma unroll
    for (int j = 0; j < 16; ++j) {
        l0 = fmaf(h[j], w2[j*3+0], l0);
        l1 = fmaf(h[j], w2[j*3+1], l1);
        l2 = fmaf(h[j], w2[j*3+2], l2);
    }
    float mx = fmaxf(l0, fmaxf(l1, l2));
    float e0 = __expf(l0-mx), e1 = __expf(l1-mx), e2 = __expf(l2-mx);
    float inv = 1.0f / (e0+e1+e2);
    float wt0 = e0*inv, wt1 = e1*inv, wt2 = e2*inv;
    float h2[8];
    #pragma unroll
    for (int j = 0; j < 8; ++j) h2[j] = pb1[j];
    #pragma unroll
    for (int d = 0; d < DD; ++d) {
        float gd  = wt0*me[0][d] + wt1*me[1][d] + wt2*me[2][d];
        float gie = gd * iev[d];
        #pragma unroll
        for (int j = 0; j < 8; ++j) {
            h2[j] = fmaf(gie,    pw1[d*8+j],          h2[j]);
            h2[j] = fmaf(gd,     pw1[(DD+d)*8+j],     h2[j]);
            h2[j] = fmaf(iev[d], pw1[(2*DD+d)*8+j],   h2[j]);
        }
    }
    float z = pb2[0];
    #pragma unroll
    for (int j = 0; j < 8; ++j)
        z = fmaf(fmaxf(h2[j], 0.0f), pw2[j], z);
    out[b] = 1.0f / (1.0f + __expf(-z));
}

extern "C" void kernel_launch(void* const* d_in, const int* in_sizes, int n_in,
                              void* d_out, int out_size, void* d_ws, size_t ws_size,
                              hipStream_t stream) {
    const int*   gi    = (const int*)d_in[0];
    const int*   ii    = (const int*)d_in[1];
    const int*   gm    = (const int*)d_in[2];
    const float* ue    = (const float*)d_in[3];
    const float* itemb = (const float*)d_in[4];
    const float* w1    = (const float*)d_in[5];
    const float* b1    = (const float*)d_in[6];
    const float* w2    = (const float*)d_in[7];
    const float* b2    = (const float*)d_in[8];
    const float* pw1   = (const float*)d_in[9];
    const float* pb1   = (const float*)d_in[10];
    const float* pw2   = (const float*)d_in[11];
    const float* pb2   = (const float*)d_in[12];
    float* out = (float*)d_out;

    int B  = in_sizes[0];
    int NG = in_sizes[2] / 3;
    int NI = in_sizes[4] / DD;

    size_t need = ((size_t)NG * GREC + (size_t)NI * IREC) * sizeof(float);
    if (ws_size >= need) {
        float* grec = (float*)d_ws;
        float* irec = grec + (size_t)NG * GREC;
        hipLaunchKernelGGL(grp_pre, dim3((NG + 255) / 256), dim3(256), 0, stream,
                           gm, ue, w1, b1, pw1, grec, NG);
        hipLaunchKernelGGL(item_pre, dim3((NI + 255) / 256), dim3(256), 0, stream,
                           itemb, w1, pw1, pb1, irec, NI);
        hipLaunchKernelGGL(agree_main, dim3((B + 255) / 256), dim3(256), 0, stream,
                           gi, ii, grec, irec, w2, b2, pw1, pw2, pb2, out, B);
    } else {
        hipLaunchKernelGGL(agree_fwd, dim3((B + 255) / 256), dim3(256), 0, stream,
                           gi, ii, gm, ue, itemb, w1, b1, w2, b2,
                           pw1, pb1, pw2, pb2, out, B);
    }
}